// Round 3
// baseline (1518.054 us; speedup 1.0000x reference)
//
#include <hip/hip_runtime.h>
#include <hip/hip_bf16.h>

// Problem constants (B=2, D=64, H=W=96)
constexpr int B_    = 2;
constexpr int D_    = 64;
constexpr int N_    = 9216;      // 96*96
constexpr int ITERS = 4;

constexpr int MT      = 64;           // queries (m) per workgroup
constexpr int MB      = N_ / MT;      // 144 m-blocks
constexpr int KS      = 4;            // key-split factor
constexpr int KEYS_WG = N_ / KS;      // 2304 keys per workgroup
constexpr int KTILES  = KEYS_WG / 128;// 18 key tiles (128 keys each, wave takes 32)
constexpr int NWG     = B_ * MB * KS; // 1152 flash workgroups

constexpr float KBW  = 0.3f;
constexpr float STEP = 0.5f;
constexpr float C2   = 0.43280851226668905f;  // KBW * log2(e)

// LDS tile strides (elements). Chosen for 2-way (free) bank access and
// 8-byte alignment of all fragment reads.
constexpr int XT_STRIDE = 68;   // 128 rows * 68 * 2B = 17408 B
constexpr int XB_STRIDE = 132;  //  64 rows * 132 * 2B = 16896 B  (offset 17408)
constexpr int SMEM_BYTES = 17408 + 16896;   // 34304; epilogue aliases this

using short8   = __attribute__((ext_vector_type(8))) short;
using short4v  = __attribute__((ext_vector_type(4))) short;
using float16v = __attribute__((ext_vector_type(16))) float;

__device__ __forceinline__ unsigned short f2bf(float f) {
  union { float f; unsigned u; } v; v.f = f;
  unsigned u = v.u;
  unsigned r = (u + 0x7fffu + ((u >> 16) & 1u)) >> 16;   // RNE
  return (unsigned short)r;
}

#if __has_builtin(__builtin_amdgcn_cvt_pk_bf16_f32)
typedef __attribute__((ext_vector_type(2))) __bf16 bf16x2;
__device__ __forceinline__ unsigned pk2bf(float a, float b) {
  bf16x2 r = __builtin_amdgcn_cvt_pk_bf16_f32(a, b);   // low <- a, high <- b, RNE
  union { bf16x2 h; unsigned u; } v; v.h = r; return v.u;
}
#else
__device__ __forceinline__ unsigned pk2bf(float a, float b) {
  return (unsigned)f2bf(a) | ((unsigned)f2bf(b) << 16);
}
#endif

// 8-byte-granular LDS vector load/store (strides are 8B- but not 16B-aligned)
__device__ __forceinline__ short8 lds_ld8(const unsigned short* p) {
  short8 r;
  ((short4v*)&r)[0] = *(const short4v*)p;
  ((short4v*)&r)[1] = *(const short4v*)(p + 4);
  return r;
}
__device__ __forceinline__ void lds_st8(unsigned short* p, short8 v) {
  *(short4v*)p       = ((short4v*)&v)[0];
  *(short4v*)(p + 4) = ((short4v*)&v)[1];
}

// ---------------------------------------------------------------------------
// prep: x_in (fp32 [b][d][n]) -> out slice 0 (copy), Xbf bf16 [b][d][n],
//       XT bf16 [b][n][d] (LDS transpose)
// ---------------------------------------------------------------------------
__global__ void prep_kernel(const float* __restrict__ xin, float* __restrict__ out,
                            unsigned short* __restrict__ XT,
                            unsigned short* __restrict__ Xbf)
{
  const int bx = blockIdx.x;
  const int nb = bx % MB, b = bx / MB;
  const int n0 = nb * 64;
  const int tid = threadIdx.x;
  __shared__ float tile[64 * 65];

  #pragma unroll
  for (int r = 0; r < 16; ++r) {
    int idx = r * 256 + tid;
    int d = idx >> 6, j = idx & 63;
    float v = xin[((size_t)b * 64 + d) * N_ + n0 + j];
    out[(((size_t)b * 5 + 0) * 64 + d) * N_ + n0 + j] = v;
    Xbf[((size_t)b * 64 + d) * N_ + n0 + j] = f2bf(v);
    tile[d * 65 + j] = v;
  }
  __syncthreads();
  #pragma unroll
  for (int r = 0; r < 16; ++r) {
    int idx = r * 256 + tid;
    int nl = idx >> 6, d = idx & 63;
    XT[((size_t)b * N_ + n0 + nl) * 64 + d] = f2bf(tile[d * 65 + nl]);
  }
}

// ---------------------------------------------------------------------------
// flash: one (b, m-block, key-split) per workgroup; 4 waves. Each 128-key
// tile is staged into LDS with fully COALESCED global loads (the previous
// per-wave divergent fragment gathers were the bottleneck: ~32 cache lines
// per load instruction, L1-MSHR serialized at ~6 cyc/line). Each wave then
// reads its 32-key quarter's MFMA fragments from LDS (2-way banked = free).
//
//   GEMM1: S[n'][m'] = sum_d XT[n0+n'][d] * XT[m0+m'][d]
//   GEMM2: accT[m][d] += sum_n W[m][n] * Xbf[d][n]
// W moves from MFMA C-layout to A-operand layout with 4 lane^32 bpermutes.
// ---------------------------------------------------------------------------
__global__ void __launch_bounds__(256, 4) flash_kernel(
    const unsigned short* __restrict__ XT,
    const unsigned short* __restrict__ Xbf,
    float* __restrict__ pacc, float* __restrict__ pcs)
{
  const int bx   = blockIdx.x;
  const int ks   = bx & 3;
  const int mb   = (bx >> 2) % MB;
  const int b    = bx / (MB * KS);
  const int tid  = threadIdx.x;
  const int wave = tid >> 6, lane = tid & 63;
  const int c = lane & 31, h = lane >> 5;
  const int m0 = mb * MT;
  const int bpaddr = ((lane ^ 32) << 2);       // ds_bpermute byte index

  const unsigned short* XTb = XT  + (size_t)b * N_ * 64;
  const unsigned short* Xb  = Xbf + (size_t)b * 64 * N_;

  __shared__ char smem[SMEM_BYTES];
  unsigned short* sXT = (unsigned short*)smem;            // [128][XT_STRIDE]
  unsigned short* sXB = (unsigned short*)(smem + 17408);  // [64][XB_STRIDE]
  float* accbuf = (float*)smem;                           // epilogue alias
  float* csbuf  = (float*)(smem + 64 * 65 * 4);           // epilogue alias

  // resident query fragments (loaded once; divergent but negligible):
  // B-operand, lane&31 = m', k = kstep*16 + h*8 + j
  short8 qf[2][4];
  #pragma unroll
  for (int mt = 0; mt < 2; ++mt)
    #pragma unroll
    for (int k = 0; k < 4; ++k)
      qf[mt][k] = *(const short8*)(XTb + (size_t)(m0 + mt * 32 + c) * 64 + k * 16 + h * 8);

  float16v zv;
  #pragma unroll
  for (int p = 0; p < 16; ++p) zv[p] = 0.f;
  float16v acc[2][2];
  acc[0][0] = zv; acc[0][1] = zv; acc[1][0] = zv; acc[1][1] = zv;
  float cs[2] = {0.f, 0.f};

  const int xt_r = tid >> 3, xt_j = (tid & 7) * 8;    // staging coords, XT tile
  const int xb_r = tid >> 4, xb_j = (tid & 15) * 8;   // staging coords, XB tile

  int n0 = ks * KEYS_WG;
  for (int t = 0; t < KTILES; ++t, n0 += 128) {
    __syncthreads();   // previous tile fully consumed before overwrite
    // ---- coalesced staging: 128x64 XT rows + 64x128 Xb cols ----
    #pragma unroll
    for (int i = 0; i < 4; ++i) {
      int r = i * 32 + xt_r;
      short8 v = *(const short8*)(XTb + (size_t)(n0 + r) * 64 + xt_j);
      lds_st8(sXT + r * XT_STRIDE + xt_j, v);
    }
    #pragma unroll
    for (int i = 0; i < 4; ++i) {
      int r = i * 16 + xb_r;
      short8 v = *(const short8*)(Xb + (size_t)r * N_ + n0 + xb_j);
      lds_st8(sXB + r * XB_STRIDE + xb_j, v);
    }
    __syncthreads();

    // ---- per-wave fragments from LDS (wave owns local keys wave*32..+31) ----
    short8 af[4];
    #pragma unroll
    for (int k = 0; k < 4; ++k)
      af[k] = lds_ld8(sXT + (wave * 32 + c) * XT_STRIDE + k * 16 + h * 8);
    short8 b2[2][2];
    #pragma unroll
    for (int k2 = 0; k2 < 2; ++k2)
      #pragma unroll
      for (int dt = 0; dt < 2; ++dt)
        b2[k2][dt] = lds_ld8(sXB + (dt * 32 + c) * XB_STRIDE + wave * 32 + k2 * 16 + h * 8);

    #pragma unroll
    for (int mt = 0; mt < 2; ++mt) {
      // ---- GEMM1 ----
      float16v S = zv;
      #pragma unroll
      for (int k = 0; k < 4; ++k)
        S = __builtin_amdgcn_mfma_f32_32x32x16_bf16(af[k], qf[mt][k], S, 0, 0, 0);

      // ---- exp + packed bf16 + colsum (from the rounded values) ----
      // C-layout: col m' = c, row n' = (p&3) + 8*(p>>2) + 4*h
      unsigned q[8];
      #pragma unroll
      for (int g = 0; g < 8; ++g) {
        float w0 = __builtin_amdgcn_exp2f(C2 * S[2 * g]);
        float w1 = __builtin_amdgcn_exp2f(C2 * S[2 * g + 1]);
        unsigned u = pk2bf(w0, w1);
        q[g] = u;
        union { unsigned u; float f; } lo, hi;
        lo.u = u << 16; hi.u = u & 0xffff0000u;
        cs[mt] += lo.f; cs[mt] += hi.f;
      }

      // ---- C-layout -> A-operand layout via lane^32 swaps ----
      unsigned s0 = h ? q[0] : q[2];
      unsigned s1 = h ? q[1] : q[3];
      unsigned s2 = h ? q[4] : q[6];
      unsigned s3 = h ? q[5] : q[7];
      unsigned r0 = (unsigned)__builtin_amdgcn_ds_bpermute(bpaddr, (int)s0);
      unsigned r1 = (unsigned)__builtin_amdgcn_ds_bpermute(bpaddr, (int)s1);
      unsigned r2 = (unsigned)__builtin_amdgcn_ds_bpermute(bpaddr, (int)s2);
      unsigned r3 = (unsigned)__builtin_amdgcn_ds_bpermute(bpaddr, (int)s3);

      union { unsigned d[4]; short8 s; } a20, a21;
      a20.d[0] = h ? r0   : q[0];
      a20.d[1] = h ? r1   : q[1];
      a20.d[2] = h ? q[2] : r0;
      a20.d[3] = h ? q[3] : r1;
      a21.d[0] = h ? r2   : q[4];
      a21.d[1] = h ? r3   : q[5];
      a21.d[2] = h ? q[6] : r2;
      a21.d[3] = h ? q[7] : r3;

      // ---- GEMM2: acc[m][d] += W[m][n] * X[d][n] ----
      #pragma unroll
      for (int dt = 0; dt < 2; ++dt)
        acc[mt][dt] = __builtin_amdgcn_mfma_f32_32x32x16_bf16(
            a20.s, b2[0][dt], acc[mt][dt], 0, 0, 0);
      #pragma unroll
      for (int dt = 0; dt < 2; ++dt)
        acc[mt][dt] = __builtin_amdgcn_mfma_f32_32x32x16_bf16(
            a21.s, b2[1][dt], acc[mt][dt], 0, 0, 0);
    }
  }

  // -------- epilogue: reduce 4 waves via LDS (aliases staging buffers) -----
  __syncthreads();
  for (int i = tid; i < 64 * 65; i += 256) accbuf[i] = 0.f;
  if (tid < 64) csbuf[tid] = 0.f;
  __syncthreads();

  #pragma unroll
  for (int mt = 0; mt < 2; ++mt) {
    atomicAdd(&csbuf[mt * 32 + c], cs[mt]);
    #pragma unroll
    for (int dt = 0; dt < 2; ++dt)
      #pragma unroll
      for (int p = 0; p < 16; ++p) {
        int m = mt * 32 + (p & 3) + 8 * (p >> 2) + 4 * h;
        int d = dt * 32 + c;
        atomicAdd(&accbuf[m * 65 + d], acc[mt][dt][p]);
      }
  }
  __syncthreads();

  for (int i = tid; i < 4096; i += 256)
    pacc[(size_t)bx * 4096 + i] = accbuf[(i >> 6) * 65 + (i & 63)];
  if (tid < 64) pcs[(size_t)bx * 64 + tid] = csbuf[tid];
}

// ---------------------------------------------------------------------------
// combine: sum KS partials, normalize, blend with x_cur (= out slice t),
// write out slice t+1 + next iteration's Xbf / XT (bf16).
// ---------------------------------------------------------------------------
__global__ void combine_kernel(const float* __restrict__ pacc,
                               const float* __restrict__ pcs,
                               float* __restrict__ out,
                               unsigned short* __restrict__ XT,
                               unsigned short* __restrict__ Xbf, int t)
{
  const int bx = blockIdx.x;
  const int mb = bx % MB, b = bx / MB;
  const int m0 = mb * MT;
  const int tid = threadIdx.x;
  __shared__ float accs[64 * 65];
  __shared__ float xnew[64 * 65];
  __shared__ float cst[64];
  const int base = (b * MB + mb) * KS;

  #pragma unroll
  for (int r = 0; r < 16; ++r) {
    int idx = r * 256 + tid;
    int m = idx >> 6, d = idx & 63;
    float s = 0.f;
    #pragma unroll
    for (int k = 0; k < KS; ++k) s += pacc[(size_t)(base + k) * 4096 + idx];
    accs[m * 65 + d] = s;
  }
  if (tid < 64) {
    float cv = 0.f;
    #pragma unroll
    for (int k = 0; k < KS; ++k) cv += pcs[(size_t)(base + k) * 64 + tid];
    cst[tid] = cv;
  }
  __syncthreads();

  #pragma unroll
  for (int r = 0; r < 16; ++r) {
    int idx = r * 256 + tid;
    int m = idx & 63, d = idx >> 6;       // m fastest -> coalesced global n
    float a = accs[m * 65 + d];
    size_t obase = (((size_t)b * 5 + t) * 64 + d) * N_ + m0 + m;
    float xc = out[obase];
    float v = STEP * (a / cst[m]) + (1.f - STEP) * xc;
    out[obase + (size_t)64 * N_] = v;     // slice t+1
    Xbf[((size_t)b * 64 + d) * N_ + m0 + m] = f2bf(v);
    xnew[m * 65 + d] = v;
  }
  __syncthreads();

  #pragma unroll
  for (int r = 0; r < 16; ++r) {
    int idx = r * 256 + tid;
    int m = idx >> 6, d = idx & 63;       // d fastest -> coalesced XT row
    XT[((size_t)b * N_ + m0 + m) * 64 + d] = f2bf(xnew[m * 65 + d]);
  }
}

// ---------------------------------------------------------------------------
extern "C" void kernel_launch(void* const* d_in, const int* in_sizes, int n_in,
                              void* d_out, int out_size, void* d_ws, size_t ws_size,
                              hipStream_t stream)
{
  (void)in_sizes; (void)n_in; (void)out_size; (void)ws_size;
  const float* xin = (const float*)d_in[0];
  float* out = (float*)d_out;
  char* ws = (char*)d_ws;

  // workspace layout (23,887,872 B total):
  unsigned short* XT  = (unsigned short*)(ws);             //  2,359,296 B
  unsigned short* Xbf = (unsigned short*)(ws +  2359296);  //  2,359,296 B
  float*          pacc = (float*)(ws +  4718592);          // 18,874,368 B
  float*          pcs  = (float*)(ws + 23592960);          //    294,912 B

  prep_kernel<<<B_ * MB, 256, 0, stream>>>(xin, out, XT, Xbf);
  for (int t = 0; t < ITERS; ++t) {
    flash_kernel<<<NWG, 256, 0, stream>>>(XT, Xbf, pacc, pcs);
    combine_kernel<<<B_ * MB, 256, 0, stream>>>(pacc, pcs, out, XT, Xbf, t);
  }
}

// Round 4
// 876.764 us; speedup vs baseline: 1.7314x; 1.7314x over previous
//
#include <hip/hip_runtime.h>
#include <hip/hip_bf16.h>

// Problem constants (B=2, D=64, H=W=96)
constexpr int B_    = 2;
constexpr int D_    = 64;
constexpr int N_    = 9216;      // 96*96
constexpr int ITERS = 4;

constexpr int MT      = 64;           // queries (m) per workgroup
constexpr int MB      = N_ / MT;      // 144 m-blocks
constexpr int KS      = 4;            // key-split factor
constexpr int KEYS_WG = N_ / KS;      // 2304 keys per workgroup
constexpr int KTILES  = KEYS_WG / 128;// 18 key tiles (128 keys each, wave takes 32)
constexpr int NWG     = B_ * MB * KS; // 1152 flash workgroups

constexpr float KBW  = 0.3f;
constexpr float STEP = 0.5f;
constexpr float C2   = 0.43280851226668905f;  // KBW * log2(e)

// LDS tile strides (elements), 8B-aligned rows.
constexpr int XT_STRIDE = 68;   // 128 rows * 68 * 2B = 17408 B
constexpr int XB_STRIDE = 132;  //  64 rows * 132 * 2B = 16896 B  (offset 17408)
constexpr int SMEM_BYTES = 17408 + 16896;   // 34304; epilogue aliases this

using short8   = __attribute__((ext_vector_type(8))) short;
using short4v  = __attribute__((ext_vector_type(4))) short;
using float16v = __attribute__((ext_vector_type(16))) float;

__device__ __forceinline__ unsigned short f2bf(float f) {
  union { float f; unsigned u; } v; v.f = f;
  unsigned u = v.u;
  unsigned r = (u + 0x7fffu + ((u >> 16) & 1u)) >> 16;   // RNE
  return (unsigned short)r;
}

#if __has_builtin(__builtin_amdgcn_cvt_pk_bf16_f32)
typedef __attribute__((ext_vector_type(2))) __bf16 bf16x2;
__device__ __forceinline__ unsigned pk2bf(float a, float b) {
  bf16x2 r = __builtin_amdgcn_cvt_pk_bf16_f32(a, b);   // low <- a, high <- b, RNE
  union { bf16x2 h; unsigned u; } v; v.h = r; return v.u;
}
#else
__device__ __forceinline__ unsigned pk2bf(float a, float b) {
  return (unsigned)f2bf(a) | ((unsigned)f2bf(b) << 16);
}
#endif

// 8-byte-granular LDS vector load/store (strides are 8B- but not 16B-aligned)
__device__ __forceinline__ short8 lds_ld8(const unsigned short* p) {
  short8 r;
  ((short4v*)&r)[0] = *(const short4v*)p;
  ((short4v*)&r)[1] = *(const short4v*)(p + 4);
  return r;
}
__device__ __forceinline__ void lds_st8(unsigned short* p, short8 v) {
  *(short4v*)p       = ((short4v*)&v)[0];
  *(short4v*)(p + 4) = ((short4v*)&v)[1];
}

// ---------------------------------------------------------------------------
// prep: x_in (fp32 [b][d][n]) -> out slice 0 (copy), Xbf bf16 [b][d][n],
//       XT bf16 [b][n][d] (LDS transpose)
// ---------------------------------------------------------------------------
__global__ void prep_kernel(const float* __restrict__ xin, float* __restrict__ out,
                            unsigned short* __restrict__ XT,
                            unsigned short* __restrict__ Xbf)
{
  const int bx = blockIdx.x;
  const int nb = bx % MB, b = bx / MB;
  const int n0 = nb * 64;
  const int tid = threadIdx.x;
  __shared__ float tile[64 * 65];

  #pragma unroll
  for (int r = 0; r < 16; ++r) {
    int idx = r * 256 + tid;
    int d = idx >> 6, j = idx & 63;
    float v = xin[((size_t)b * 64 + d) * N_ + n0 + j];
    out[(((size_t)b * 5 + 0) * 64 + d) * N_ + n0 + j] = v;
    Xbf[((size_t)b * 64 + d) * N_ + n0 + j] = f2bf(v);
    tile[d * 65 + j] = v;
  }
  __syncthreads();
  #pragma unroll
  for (int r = 0; r < 16; ++r) {
    int idx = r * 256 + tid;
    int nl = idx >> 6, d = idx & 63;
    XT[((size_t)b * N_ + n0 + nl) * 64 + d] = f2bf(tile[d * 65 + nl]);
  }
}

// ---------------------------------------------------------------------------
// flash: one (b, m-block, key-split) per workgroup; 4 waves. Each 128-key
// tile is staged into LDS with fully COALESCED global loads, then each wave
// reads its 32-key quarter's MFMA fragments from LDS.
//
// __launch_bounds__(256,3): round 3's (256,4) capped the unified reg budget
// at 128 (< 64 AGPR acc + ~92 VGPR needed) -> massive scratch spill (431 MB
// HBM fetch/dispatch). 3 waves/EU gives a 170-reg budget; measured need ~156.
//
//   GEMM1: S[n'][m'] = sum_d XT[n0+n'][d] * XT[m0+m'][d]
//   GEMM2: accT[m][d] += sum_n W[m][n] * Xbf[d][n]
// W moves from MFMA C-layout to A-operand layout with 4 lane^32 bpermutes.
// ---------------------------------------------------------------------------
__global__ void __launch_bounds__(256, 3) flash_kernel(
    const unsigned short* __restrict__ XT,
    const unsigned short* __restrict__ Xbf,
    float* __restrict__ pacc, float* __restrict__ pcs)
{
  const int bx   = blockIdx.x;
  const int ks   = bx & 3;
  const int mb   = (bx >> 2) % MB;
  const int b    = bx / (MB * KS);
  const int tid  = threadIdx.x;
  const int wave = tid >> 6, lane = tid & 63;
  const int c = lane & 31, h = lane >> 5;
  const int m0 = mb * MT;
  const int bpaddr = ((lane ^ 32) << 2);       // ds_bpermute byte index

  const unsigned short* XTb = XT  + (size_t)b * N_ * 64;
  const unsigned short* Xb  = Xbf + (size_t)b * 64 * N_;

  __shared__ char smem[SMEM_BYTES];
  unsigned short* sXT = (unsigned short*)smem;            // [128][XT_STRIDE]
  unsigned short* sXB = (unsigned short*)(smem + 17408);  // [64][XB_STRIDE]
  float* accbuf = (float*)smem;                           // epilogue alias
  float* csbuf  = (float*)(smem + 64 * 65 * 4);           // epilogue alias

  // resident query fragments: B-operand, lane&31 = m', k = kstep*16 + h*8 + j
  short8 qf[2][4];
  #pragma unroll
  for (int mt = 0; mt < 2; ++mt)
    #pragma unroll
    for (int k = 0; k < 4; ++k)
      qf[mt][k] = *(const short8*)(XTb + (size_t)(m0 + mt * 32 + c) * 64 + k * 16 + h * 8);

  float16v zv;
  #pragma unroll
  for (int p = 0; p < 16; ++p) zv[p] = 0.f;
  float16v acc[2][2];
  acc[0][0] = zv; acc[0][1] = zv; acc[1][0] = zv; acc[1][1] = zv;
  float cs[2] = {0.f, 0.f};

  const int xt_r = tid >> 3, xt_j = (tid & 7) * 8;    // staging coords, XT tile
  const int xb_r = tid >> 4, xb_j = (tid & 15) * 8;   // staging coords, XB tile

  int n0 = ks * KEYS_WG;
  for (int t = 0; t < KTILES; ++t, n0 += 128) {
    __syncthreads();   // previous tile fully consumed before overwrite
    // ---- coalesced staging: 128x64 XT rows + 64x128 Xb cols ----
    #pragma unroll
    for (int i = 0; i < 4; ++i) {
      int r = i * 32 + xt_r;
      short8 v = *(const short8*)(XTb + (size_t)(n0 + r) * 64 + xt_j);
      lds_st8(sXT + r * XT_STRIDE + xt_j, v);
    }
    #pragma unroll
    for (int i = 0; i < 4; ++i) {
      int r = i * 16 + xb_r;
      short8 v = *(const short8*)(Xb + (size_t)r * N_ + n0 + xb_j);
      lds_st8(sXB + r * XB_STRIDE + xb_j, v);
    }
    __syncthreads();

    // ---- per-wave fragments from LDS (wave owns local keys wave*32..+31) ----
    short8 af[4];
    #pragma unroll
    for (int k = 0; k < 4; ++k)
      af[k] = lds_ld8(sXT + (wave * 32 + c) * XT_STRIDE + k * 16 + h * 8);
    short8 b2[2][2];
    #pragma unroll
    for (int k2 = 0; k2 < 2; ++k2)
      #pragma unroll
      for (int dt = 0; dt < 2; ++dt)
        b2[k2][dt] = lds_ld8(sXB + (dt * 32 + c) * XB_STRIDE + wave * 32 + k2 * 16 + h * 8);

    #pragma unroll
    for (int mt = 0; mt < 2; ++mt) {
      // ---- GEMM1 ----
      float16v S = zv;
      #pragma unroll
      for (int k = 0; k < 4; ++k)
        S = __builtin_amdgcn_mfma_f32_32x32x16_bf16(af[k], qf[mt][k], S, 0, 0, 0);

      // ---- exp + packed bf16 + colsum (from the rounded values) ----
      // C-layout: col m' = c, row n' = (p&3) + 8*(p>>2) + 4*h
      unsigned q[8];
      #pragma unroll
      for (int g = 0; g < 8; ++g) {
        float w0 = __builtin_amdgcn_exp2f(C2 * S[2 * g]);
        float w1 = __builtin_amdgcn_exp2f(C2 * S[2 * g + 1]);
        unsigned u = pk2bf(w0, w1);
        q[g] = u;
        union { unsigned u; float f; } lo, hi;
        lo.u = u << 16; hi.u = u & 0xffff0000u;
        cs[mt] += lo.f; cs[mt] += hi.f;
      }

      // ---- C-layout -> A-operand layout via lane^32 swaps ----
      unsigned s0 = h ? q[0] : q[2];
      unsigned s1 = h ? q[1] : q[3];
      unsigned s2 = h ? q[4] : q[6];
      unsigned s3 = h ? q[5] : q[7];
      unsigned r0 = (unsigned)__builtin_amdgcn_ds_bpermute(bpaddr, (int)s0);
      unsigned r1 = (unsigned)__builtin_amdgcn_ds_bpermute(bpaddr, (int)s1);
      unsigned r2 = (unsigned)__builtin_amdgcn_ds_bpermute(bpaddr, (int)s2);
      unsigned r3 = (unsigned)__builtin_amdgcn_ds_bpermute(bpaddr, (int)s3);

      union { unsigned d[4]; short8 s; } a20, a21;
      a20.d[0] = h ? r0   : q[0];
      a20.d[1] = h ? r1   : q[1];
      a20.d[2] = h ? q[2] : r0;
      a20.d[3] = h ? q[3] : r1;
      a21.d[0] = h ? r2   : q[4];
      a21.d[1] = h ? r3   : q[5];
      a21.d[2] = h ? q[6] : r2;
      a21.d[3] = h ? q[7] : r3;

      // ---- GEMM2: acc[m][d] += W[m][n] * X[d][n] ----
      #pragma unroll
      for (int dt = 0; dt < 2; ++dt)
        acc[mt][dt] = __builtin_amdgcn_mfma_f32_32x32x16_bf16(
            a20.s, b2[0][dt], acc[mt][dt], 0, 0, 0);
      #pragma unroll
      for (int dt = 0; dt < 2; ++dt)
        acc[mt][dt] = __builtin_amdgcn_mfma_f32_32x32x16_bf16(
            a21.s, b2[1][dt], acc[mt][dt], 0, 0, 0);
    }
  }

  // -------- epilogue: reduce 4 waves via LDS (aliases staging buffers) -----
  __syncthreads();
  for (int i = tid; i < 64 * 65; i += 256) accbuf[i] = 0.f;
  if (tid < 64) csbuf[tid] = 0.f;
  __syncthreads();

  #pragma unroll
  for (int mt = 0; mt < 2; ++mt) {
    atomicAdd(&csbuf[mt * 32 + c], cs[mt]);
    #pragma unroll
    for (int dt = 0; dt < 2; ++dt)
      #pragma unroll
      for (int p = 0; p < 16; ++p) {
        int m = mt * 32 + (p & 3) + 8 * (p >> 2) + 4 * h;
        int d = dt * 32 + c;
        atomicAdd(&accbuf[m * 65 + d], acc[mt][dt][p]);
      }
  }
  __syncthreads();

  for (int i = tid; i < 4096; i += 256)
    pacc[(size_t)bx * 4096 + i] = accbuf[(i >> 6) * 65 + (i & 63)];
  if (tid < 64) pcs[(size_t)bx * 64 + tid] = csbuf[tid];
}

// ---------------------------------------------------------------------------
// combine: sum KS partials, normalize, blend with x_cur (= out slice t),
// write out slice t+1 + next iteration's Xbf / XT (bf16).
// ---------------------------------------------------------------------------
__global__ void combine_kernel(const float* __restrict__ pacc,
                               const float* __restrict__ pcs,
                               float* __restrict__ out,
                               unsigned short* __restrict__ XT,
                               unsigned short* __restrict__ Xbf, int t)
{
  const int bx = blockIdx.x;
  const int mb = bx % MB, b = bx / MB;
  const int m0 = mb * MT;
  const int tid = threadIdx.x;
  __shared__ float accs[64 * 65];
  __shared__ float xnew[64 * 65];
  __shared__ float cst[64];
  const int base = (b * MB + mb) * KS;

  #pragma unroll
  for (int r = 0; r < 16; ++r) {
    int idx = r * 256 + tid;
    int m = idx >> 6, d = idx & 63;
    float s = 0.f;
    #pragma unroll
    for (int k = 0; k < KS; ++k) s += pacc[(size_t)(base + k) * 4096 + idx];
    accs[m * 65 + d] = s;
  }
  if (tid < 64) {
    float cv = 0.f;
    #pragma unroll
    for (int k = 0; k < KS; ++k) cv += pcs[(size_t)(base + k) * 64 + tid];
    cst[tid] = cv;
  }
  __syncthreads();

  #pragma unroll
  for (int r = 0; r < 16; ++r) {
    int idx = r * 256 + tid;
    int m = idx & 63, d = idx >> 6;       // m fastest -> coalesced global n
    float a = accs[m * 65 + d];
    size_t obase = (((size_t)b * 5 + t) * 64 + d) * N_ + m0 + m;
    float xc = out[obase];
    float v = STEP * (a / cst[m]) + (1.f - STEP) * xc;
    out[obase + (size_t)64 * N_] = v;     // slice t+1
    Xbf[((size_t)b * 64 + d) * N_ + m0 + m] = f2bf(v);
    xnew[m * 65 + d] = v;
  }
  __syncthreads();

  #pragma unroll
  for (int r = 0; r < 16; ++r) {
    int idx = r * 256 + tid;
    int m = idx >> 6, d = idx & 63;       // d fastest -> coalesced XT row
    XT[((size_t)b * N_ + m0 + m) * 64 + d] = f2bf(xnew[m * 65 + d]);
  }
}

// ---------------------------------------------------------------------------
extern "C" void kernel_launch(void* const* d_in, const int* in_sizes, int n_in,
                              void* d_out, int out_size, void* d_ws, size_t ws_size,
                              hipStream_t stream)
{
  (void)in_sizes; (void)n_in; (void)out_size; (void)ws_size;
  const float* xin = (const float*)d_in[0];
  float* out = (float*)d_out;
  char* ws = (char*)d_ws;

  // workspace layout (23,887,872 B total):
  unsigned short* XT  = (unsigned short*)(ws);             //  2,359,296 B
  unsigned short* Xbf = (unsigned short*)(ws +  2359296);  //  2,359,296 B
  float*          pacc = (float*)(ws +  4718592);          // 18,874,368 B
  float*          pcs  = (float*)(ws + 23592960);          //    294,912 B

  prep_kernel<<<B_ * MB, 256, 0, stream>>>(xin, out, XT, Xbf);
  for (int t = 0; t < ITERS; ++t) {
    flash_kernel<<<NWG, 256, 0, stream>>>(XT, Xbf, pacc, pcs);
    combine_kernel<<<B_ * MB, 256, 0, stream>>>(pacc, pcs, out, XT, Xbf, t);
  }
}

// Round 5
// 478.157 us; speedup vs baseline: 3.1748x; 1.8336x over previous
//
#include <hip/hip_runtime.h>
#include <hip/hip_bf16.h>

// Problem constants (B=2, D=64, H=W=96)
constexpr int B_    = 2;
constexpr int D_    = 64;
constexpr int N_    = 9216;      // 96*96
constexpr int ITERS = 4;

constexpr int MTQ     = 128;          // queries per workgroup (m-split: 32/wave)
constexpr int MBF     = N_ / MTQ;     // 72 m-blocks
constexpr int KS      = 4;            // key-split factor
constexpr int KEYS_WG = N_ / KS;      // 2304 keys per workgroup
constexpr int KTILES  = KEYS_WG / 128;// 18 key tiles of 128
constexpr int NWG     = B_ * MBF * KS;// 576 flash workgroups
constexpr int PB      = 144;          // prep n-blocks of 64

constexpr float KBW  = 0.3f;
constexpr float STEP = 0.5f;
constexpr float C2   = 0.43280851226668905f;  // KBW * log2(e)

using short8   = __attribute__((ext_vector_type(8))) short;
using float16v = __attribute__((ext_vector_type(16))) float;

__device__ __forceinline__ unsigned short f2bf(float f) {
  union { float f; unsigned u; } v; v.f = f;
  unsigned u = v.u;
  unsigned r = (u + 0x7fffu + ((u >> 16) & 1u)) >> 16;   // RNE
  return (unsigned short)r;
}

#if __has_builtin(__builtin_amdgcn_cvt_pk_bf16_f32)
typedef __attribute__((ext_vector_type(2))) __bf16 bf16x2;
__device__ __forceinline__ unsigned pk2bf(float a, float b) {
  bf16x2 r = __builtin_amdgcn_cvt_pk_bf16_f32(a, b);   // low <- a, high <- b, RNE
  union { bf16x2 h; unsigned u; } v; v.h = r; return v.u;
}
#else
__device__ __forceinline__ unsigned pk2bf(float a, float b) {
  return (unsigned)f2bf(a) | ((unsigned)f2bf(b) << 16);
}
#endif

// Async global->LDS DMA, 16 B/lane. lds_base must be wave-uniform; HW writes
// lane i at lds_base + i*16 (m104). Global address is per-lane (gather OK).
__device__ __forceinline__ void dma16(const unsigned short* g,
                                      unsigned short* lds_base, int lane) {
#if __has_builtin(__builtin_amdgcn_global_load_lds)
  __builtin_amdgcn_global_load_lds(
      (const __attribute__((address_space(1))) unsigned int*)g,
      (__attribute__((address_space(3))) unsigned int*)lds_base, 16, 0, 0);
#else
  *(int4*)((char*)lds_base + lane * 16) = *(const int4*)g;
#endif
}

// ---------------------------------------------------------------------------
// prep: x_in (fp32 [b][d][n]) -> out slice 0 (copy), Xbf bf16 [b][d][n],
//       XT bf16 [b][n][d] (LDS transpose)
// ---------------------------------------------------------------------------
__global__ void prep_kernel(const float* __restrict__ xin, float* __restrict__ out,
                            unsigned short* __restrict__ XT,
                            unsigned short* __restrict__ Xbf)
{
  const int bx = blockIdx.x;
  const int nb = bx % PB, b = bx / PB;
  const int n0 = nb * 64;
  const int tid = threadIdx.x;
  __shared__ float tile[64 * 65];

  #pragma unroll
  for (int r = 0; r < 16; ++r) {
    int idx = r * 256 + tid;
    int d = idx >> 6, j = idx & 63;
    float v = xin[((size_t)b * 64 + d) * N_ + n0 + j];
    out[(((size_t)b * 5 + 0) * 64 + d) * N_ + n0 + j] = v;
    Xbf[((size_t)b * 64 + d) * N_ + n0 + j] = f2bf(v);
    tile[d * 65 + j] = v;
  }
  __syncthreads();
  #pragma unroll
  for (int r = 0; r < 16; ++r) {
    int idx = r * 256 + tid;
    int nl = idx >> 6, d = idx & 63;
    XT[((size_t)b * N_ + n0 + nl) * 64 + d] = f2bf(tile[d * 65 + nl]);
  }
}

// ---------------------------------------------------------------------------
// flash: wg = (b, 128-query m-block, key-split). m-SPLIT waves: wave w owns
// queries m0+w*32..+31; all 4 waves share each staged 128-key tile (halves
// per-CU L1-miss traffic vs key-split). Staging via global_load_lds with an
// XOR swizzle applied on the GLOBAL address (gc = sc ^ (row&7)) so canonical
// DMA placement yields 4-way-max bank access on fragment ds_read_b128s.
// Outputs are wave-disjoint -> no epilogue reduction, no atomics.
//
//   GEMM1: S[n'][m'] = sum_d XT[key][d] * XT[query][d]
//   GEMM2: acc[m][d] += sum_n W[m][n] * Xbf[d][n]
// ---------------------------------------------------------------------------
__global__ void __launch_bounds__(256, 3) flash_kernel(
    const unsigned short* __restrict__ XT,
    const unsigned short* __restrict__ Xbf,
    float* __restrict__ pacc, float* __restrict__ pcs)
{
  const int bx   = blockIdx.x;
  const int ks   = bx & 3;
  const int mb   = (bx >> 2) % MBF;
  const int b    = bx / (MBF * KS);
  const int tid  = threadIdx.x;
  const int wave = tid >> 6, lane = tid & 63;
  const int c = lane & 31, h = lane >> 5;
  const int m0 = mb * MTQ;
  const int bpaddr = (lane ^ 32) << 2;      // ds_bpermute byte index

  const unsigned short* XTb = XT  + (size_t)b * N_ * 64;
  const unsigned short* Xb  = Xbf + (size_t)b * 64 * N_;

  __shared__ unsigned short sXT[128 * 64];  // [key][d], chunk-swizzled
  __shared__ unsigned short sXB[64 * 128];  // [d][n],  chunk-swizzled

  // wave's resident query fragments (B-operand): lane&31 = m', once per kernel
  short8 qf[4];
  #pragma unroll
  for (int k = 0; k < 4; ++k)
    qf[k] = *(const short8*)(XTb + (size_t)(m0 + wave * 32 + c) * 64 + k * 16 + h * 8);

  float16v zv;
  #pragma unroll
  for (int p = 0; p < 16; ++p) zv[p] = 0.f;
  float16v acc[2];
  acc[0] = zv; acc[1] = zv;
  float cs = 0.f;

  // DMA lane coords
  const int xt_rr = lane >> 3, xt_sc = lane & 7;   // 8 rows x 8 chunks per instr
  const int xb_rr = lane >> 4, xb_sc = lane & 15;  // 4 rows x 16 chunks per instr

  int n0g = ks * KEYS_WG;
  for (int t = 0; t < KTILES; ++t, n0g += 128) {
    __syncthreads();   // prior tile fully consumed
    // ---- DMA staging; swizzle on global side: LDS[row][sc] = chunk sc^(row&7)
    #pragma unroll
    for (int ii = 0; ii < 4; ++ii) {
      int row = wave * 32 + ii * 8 + xt_rr;                 // key row
      int gc  = xt_sc ^ (row & 7);
      dma16(XTb + (size_t)(n0g + row) * 64 + gc * 8,
            sXT + (wave * 32 + ii * 8) * 64, lane);
    }
    #pragma unroll
    for (int ii = 0; ii < 4; ++ii) {
      int row = wave * 16 + ii * 4 + xb_rr;                 // d row
      int gc  = xb_sc ^ (row & 7);
      dma16(Xb + (size_t)row * N_ + n0g + gc * 8,
            sXB + (wave * 16 + ii * 4) * 128, lane);
    }
    __syncthreads();   // drains vmcnt -> tile ready

    #pragma unroll
    for (int s = 0; s < 4; ++s) {           // 4 key subtiles of 32
      // A-frags (keys): row = s*32+c, chunk gc = k*2+h, slot = gc^(c&7)
      short8 af[4];
      #pragma unroll
      for (int k = 0; k < 4; ++k)
        af[k] = *(const short8*)(sXT + (s * 32 + c) * 64 + ((k * 2 + h) ^ (c & 7)) * 8);

      float16v S = zv;
      #pragma unroll
      for (int k = 0; k < 4; ++k)
        S = __builtin_amdgcn_mfma_f32_32x32x16_bf16(af[k], qf[k], S, 0, 0, 0);

      // exp + pack; colsum from the ROUNDED weights (self-term cancels exactly)
      unsigned q[8];
      #pragma unroll
      for (int g = 0; g < 8; ++g) {
        float w0 = __builtin_amdgcn_exp2f(C2 * S[2 * g]);
        float w1 = __builtin_amdgcn_exp2f(C2 * S[2 * g + 1]);
        unsigned u = pk2bf(w0, w1);
        q[g] = u;
        union { unsigned u; float f; } lo, hi;
        lo.u = u << 16; hi.u = u & 0xffff0000u;
        cs += lo.f; cs += hi.f;
      }

      // C-layout -> A-operand layout via lane^32 swaps (verified R1-R4)
      unsigned s0 = h ? q[0] : q[2];
      unsigned s1 = h ? q[1] : q[3];
      unsigned s2 = h ? q[4] : q[6];
      unsigned s3 = h ? q[5] : q[7];
      unsigned r0 = (unsigned)__builtin_amdgcn_ds_bpermute(bpaddr, (int)s0);
      unsigned r1 = (unsigned)__builtin_amdgcn_ds_bpermute(bpaddr, (int)s1);
      unsigned r2 = (unsigned)__builtin_amdgcn_ds_bpermute(bpaddr, (int)s2);
      unsigned r3 = (unsigned)__builtin_amdgcn_ds_bpermute(bpaddr, (int)s3);

      union { unsigned d[4]; short8 s; } a20, a21;
      a20.d[0] = h ? r0   : q[0];
      a20.d[1] = h ? r1   : q[1];
      a20.d[2] = h ? q[2] : r0;
      a20.d[3] = h ? q[3] : r1;
      a21.d[0] = h ? r2   : q[4];
      a21.d[1] = h ? r3   : q[5];
      a21.d[2] = h ? q[6] : r2;
      a21.d[3] = h ? q[7] : r3;

      // B-frags (X): row = dt*32+c, gc = k2*2+h with k2 = 2s, 2s+1
      short8 b20[2], b21[2];
      #pragma unroll
      for (int dt = 0; dt < 2; ++dt) {
        b20[dt] = *(const short8*)(sXB + (dt * 32 + c) * 128 + ((4 * s + h)     ^ (c & 7)) * 8);
        b21[dt] = *(const short8*)(sXB + (dt * 32 + c) * 128 + ((4 * s + 2 + h) ^ (c & 7)) * 8);
      }
      #pragma unroll
      for (int dt = 0; dt < 2; ++dt)
        acc[dt] = __builtin_amdgcn_mfma_f32_32x32x16_bf16(a20.s, b20[dt], acc[dt], 0, 0, 0);
      #pragma unroll
      for (int dt = 0; dt < 2; ++dt)
        acc[dt] = __builtin_amdgcn_mfma_f32_32x32x16_bf16(a21.s, b21[dt], acc[dt], 0, 0, 0);
    }
  }

  // -------- epilogue: wave-disjoint outputs, direct global writes ----------
  union { float f; int i; } cu; cu.f = cs;
  cu.i = __builtin_amdgcn_ds_bpermute(bpaddr, cu.i);
  float cst = cs + cu.f;                     // both h-halves hold the total
  if (h == 0) pcs[(size_t)bx * 128 + wave * 32 + c] = cst;

  float* pw = pacc + (size_t)bx * (MTQ * 64);
  #pragma unroll
  for (int dt = 0; dt < 2; ++dt)
    #pragma unroll
    for (int p = 0; p < 16; ++p) {
      int m = wave * 32 + (p & 3) + 8 * (p >> 2) + 4 * h;
      pw[m * 64 + dt * 32 + c] = acc[dt][p];
    }
}

// ---------------------------------------------------------------------------
// combine: sum KS partials, normalize, blend with x_cur (= out slice t),
// write out slice t+1 + next iteration's Xbf / XT (bf16). grid: B_*MBF.
// ---------------------------------------------------------------------------
__global__ void combine_kernel(const float* __restrict__ pacc,
                               const float* __restrict__ pcs,
                               float* __restrict__ out,
                               unsigned short* __restrict__ XT,
                               unsigned short* __restrict__ Xbf, int t)
{
  const int bx = blockIdx.x;
  const int mb = bx % MBF, b = bx / MBF;
  const int m0 = mb * MTQ;
  const int tid = threadIdx.x;
  __shared__ float accs[128 * 65];
  __shared__ float cst[128];
  const int base = (b * MBF + mb) * KS;

  #pragma unroll
  for (int r = 0; r < 32; ++r) {
    int idx = r * 256 + tid;                  // m = idx>>6, d = idx&63
    float s = 0.f;
    #pragma unroll
    for (int k = 0; k < KS; ++k) s += pacc[(size_t)(base + k) * 8192 + idx];
    accs[(idx >> 6) * 65 + (idx & 63)] = s;
  }
  if (tid < 128) {
    float cv = 0.f;
    #pragma unroll
    for (int k = 0; k < KS; ++k) cv += pcs[(size_t)(base + k) * 128 + tid];
    cst[tid] = cv;
  }
  __syncthreads();

  #pragma unroll
  for (int r = 0; r < 32; ++r) {
    int idx = r * 256 + tid;
    int m = idx & 127, d = idx >> 7;          // m fastest -> coalesced global n
    float a = accs[m * 65 + d];
    size_t obase = (((size_t)b * 5 + t) * 64 + d) * N_ + m0 + m;
    float xc = out[obase];
    float v = STEP * (a / cst[m]) + (1.f - STEP) * xc;
    out[obase + (size_t)64 * N_] = v;         // slice t+1
    Xbf[((size_t)b * 64 + d) * N_ + m0 + m] = f2bf(v);
    accs[m * 65 + d] = v;                     // in-place for transpose pass
  }
  __syncthreads();

  #pragma unroll
  for (int r = 0; r < 32; ++r) {
    int idx = r * 256 + tid;
    int m = idx >> 6, d = idx & 63;           // d fastest -> coalesced XT row
    XT[((size_t)b * N_ + m0 + m) * 64 + d] = f2bf(accs[m * 65 + d]);
  }
}

// ---------------------------------------------------------------------------
extern "C" void kernel_launch(void* const* d_in, const int* in_sizes, int n_in,
                              void* d_out, int out_size, void* d_ws, size_t ws_size,
                              hipStream_t stream)
{
  (void)in_sizes; (void)n_in; (void)out_size; (void)ws_size;
  const float* xin = (const float*)d_in[0];
  float* out = (float*)d_out;
  char* ws = (char*)d_ws;

  // workspace layout (23,887,872 B total — same footprint as R1-R4):
  unsigned short* XT  = (unsigned short*)(ws);             //  2,359,296 B
  unsigned short* Xbf = (unsigned short*)(ws +  2359296);  //  2,359,296 B
  float*          pacc = (float*)(ws +  4718592);          // 18,874,368 B (576*8192*4)
  float*          pcs  = (float*)(ws + 23592960);          //    294,912 B (576*128*4)

  prep_kernel<<<B_ * PB, 256, 0, stream>>>(xin, out, XT, Xbf);
  for (int t = 0; t < ITERS; ++t) {
    flash_kernel<<<NWG, 256, 0, stream>>>(XT, Xbf, pacc, pcs);
    combine_kernel<<<B_ * MBF, 256, 0, stream>>>(pacc, pcs, out, XT, Xbf, t);
  }
}